// Round 9
// baseline (34057.074 us; speedup 1.0000x reference)
//
#include <hip/hip_runtime.h>

// GRU rollout decoder, MI355X. bf16x3 (hi/lo split) MFMA GEMMs, fp32 accumulate.
// R7/R8: PERSISTENT single kernel. R3 measured 7.38ms = ~11us/step in-kernel +
// ~17us/step launch-boundary residual (512 dependent dispatches). This kernel
// runs all 256 steps in ONE launch: 256 blocks (90KB LDS -> 1 block/CU -> all
// co-resident), manual grid barrier (unique counter per barrier + agent fences).
// Cell phase = R3 cell verbatim (512thr, K-step 64, 20/16 phases, setprio).
// Head phase = R3 math, but staged by all 512 threads (3 slots/thread).

typedef __attribute__((ext_vector_type(8))) short bf16x8;
typedef __attribute__((ext_vector_type(4))) float f32x4;
typedef __attribute__((ext_vector_type(8))) unsigned short us8;

#define I_ 256
#define H_ 1024
#define B_ 512
#define L_ 256
#define NBLK 256

#define MFMA(A, Bm, C) C = __builtin_amdgcn_mfma_f32_16x16x32_bf16(A, Bm, C, 0, 0, 0)

__device__ __forceinline__ unsigned short f2bf(float f) {
  unsigned u = __float_as_uint(f);
  u += 0x7FFFu + ((u >> 16) & 1u);   // round-to-nearest-even
  return (unsigned short)(u >> 16);
}
__device__ __forceinline__ float bf2f(unsigned short s) {
  return __uint_as_float(((unsigned)s) << 16);
}

// ---------------------------------------------------------------------------
// prep: split W_hh, W_ih, W_head, context into bf16 hi/lo pairs; zero barriers
// ---------------------------------------------------------------------------
__global__ void gru_prep(const float* __restrict__ whh, const float* __restrict__ wih,
                         const float* __restrict__ whd, const float* __restrict__ ctx,
                         unsigned short* __restrict__ whh_h, unsigned short* __restrict__ whh_l,
                         unsigned short* __restrict__ wih_h, unsigned short* __restrict__ wih_l,
                         unsigned short* __restrict__ whd_h, unsigned short* __restrict__ whd_l,
                         unsigned short* __restrict__ hh, unsigned short* __restrict__ hl,
                         unsigned* __restrict__ bar) {
  const int gid = blockIdx.x * blockDim.x + threadIdx.x;
  if (gid < 2 * L_) bar[gid] = 0;   // barrier counters (visible at next dispatch)
  const int NWHH = 3 * H_ * H_;
  const int NWIH = 3 * H_ * I_;
  const int NWHD = I_ * H_;
  const int NCTX = B_ * H_;
  const int tot = NWHH + NWIH + NWHD + NCTX;
  for (int idx = gid; idx < tot; idx += gridDim.x * blockDim.x) {
    const float* src; unsigned short* dh; unsigned short* dl; int off;
    if (idx < NWHH) { src = whh; dh = whh_h; dl = whh_l; off = idx; }
    else if (idx < NWHH + NWIH) { src = wih; dh = wih_h; dl = wih_l; off = idx - NWHH; }
    else if (idx < NWHH + NWIH + NWHD) { src = whd; dh = whd_h; dl = whd_l; off = idx - NWHH - NWIH; }
    else { src = ctx; dh = hh; dl = hl; off = idx - NWHH - NWIH - NWHD; }
    float v = src[off];
    unsigned short h = f2bf(v);
    dh[off] = h;
    dl[off] = f2bf(v - bf2f(h));
  }
}

// ---------------------------------------------------------------------------
// grid barrier: unique counter per use (prep zeroes them). release fence ->
// arrive -> spin -> acquire fence. All 256 blocks co-resident by construction.
// ---------------------------------------------------------------------------
__device__ __forceinline__ void gbar(unsigned* cnt) {
  __builtin_amdgcn_fence(__ATOMIC_RELEASE, "agent");
  __syncthreads();
  if (threadIdx.x == 0) {
    __hip_atomic_fetch_add(cnt, 1u, __ATOMIC_RELAXED, __HIP_MEMORY_SCOPE_AGENT);
    while (__hip_atomic_load(cnt, __ATOMIC_RELAXED, __HIP_MEMORY_SCOPE_AGENT) < (unsigned)NBLK)
      __builtin_amdgcn_s_sleep(8);
  }
  __syncthreads();
  __builtin_amdgcn_fence(__ATOMIC_ACQUIRE, "agent");
}

// ---------------------------------------------------------------------------
// persistent kernel: 256 blocks x 512 threads, loops t=0..255.
//   CELL (BM=64 x BN=32, 8 waves 4x2, K-step 64) -> gbar -> HEAD (16x32,
//   staged by 512 thr, computed by waves 0-1, K-step 128) -> gbar.
// LDS union: cell A@0 (36864B) + W@36864 (55296B) = 92160; head A@0 (17408) +
// W@17408 (34816) = 52224. Phases time-separated by gbar's syncthreads.
// ---------------------------------------------------------------------------
__global__ __launch_bounds__(512) void gru_all(
    const unsigned short* __restrict__ whh_h, const unsigned short* __restrict__ whh_l,
    const unsigned short* __restrict__ wih_h, const unsigned short* __restrict__ wih_l,
    const unsigned short* __restrict__ whd_h, const unsigned short* __restrict__ whd_l,
    const float* __restrict__ b_ih, const float* __restrict__ b_hh,
    const float* __restrict__ b_head,
    unsigned short* hh0, unsigned short* hl0,
    unsigned short* hh1, unsigned short* hl1,
    unsigned short* xh, unsigned short* xl,
    float* out, unsigned* bar) {
  __shared__ __align__(16) unsigned char smem[92160];
  unsigned short* CA = (unsigned short*)smem;            // cell A [nb][hl][64][72]
  unsigned short* CW = (unsigned short*)(smem + 36864);  // cell W [nb][hl][96][72]
  unsigned short* HA = (unsigned short*)smem;            // head A [nb][hl][16][136]
  unsigned short* HW = (unsigned short*)(smem + 17408);  // head W [nb][hl][32][136]

  const int tid = threadIdx.x;
  const int bid = blockIdx.x;
  // cell decomposition (as R3): XCD x owns jt in {4x..4x+3}
  const int xcd = bid & 7;
  const int q = bid >> 3;                 // 0..31
  const int jt = xcd * 4 + (q & 3);       // 0..31  h-col tile (32 cols)
  const int bt = q >> 2;                  // 0..7   batch tile (64 rows)
  const int wv = tid >> 6;                // wave 0..7
  const int wr = wv >> 1;                 // 16-row frag (0..3)
  const int wc = wv & 1;                  // 16-col half (0..1)
  const int lane = tid & 63;
  const int m = lane & 15;
  const int ko = (lane >> 4) << 3;        // 0,8,16,24 within 32-k chunk
  const int wj = wc * 16 + m;             // col within 32-col gate block
  const int r0 = (lane >> 4) << 2;
  // head decomposition (as R3)
  const int it = bid & 7;                 // i tile (32 cols)
  const int bt2 = bid >> 3;               // batch tile (16 rows)

  us8 rg[5];   // cell staging
  us8 hg[3];   // head staging

#pragma unroll 1
  for (int t = 0; t < L_; ++t) {
    const unsigned short* h_h = (t & 1) ? hh1 : hh0;
    const unsigned short* h_l = (t & 1) ? hl1 : hl0;
    unsigned short* ho_h = (t & 1) ? hh0 : hh1;
    unsigned short* ho_l = (t & 1) ? hl0 : hl1;

    // ======================= CELL =======================
    f32x4 accR = {}, accZ = {}, accGin = {}, accGhn = {};

    auto load_phase = [&](int p) {
      const unsigned short *Ah_s, *Al_s, *Wh_s, *Wl_s;
      int kb, ldA, ldW;
      if (p < 16) { Ah_s = h_h; Al_s = h_l; Wh_s = whh_h; Wl_s = whh_l; kb = p << 6; ldA = H_; ldW = H_; }
      else        { Ah_s = xh;  Al_s = xl;  Wh_s = wih_h; Wl_s = wih_l; kb = (p - 16) << 6; ldA = I_; ldW = I_; }
#pragma unroll
      for (int i = 0; i < 2; ++i) {  // A: 2hl x 64 rows x 8 ss = 1024 slots
        int t2 = i * 512 + tid;
        int hl2 = t2 >> 9, rem = t2 & 511;
        int rr = rem >> 3, ss = rem & 7;
        const unsigned short* s = hl2 ? Al_s : Ah_s;
        rg[i] = *(const us8*)&s[(bt * 64 + rr) * ldA + kb + ss * 8];
      }
#pragma unroll
      for (int i = 2; i < 5; ++i) {  // W: 2hl x 96 rows x 8 ss = 1536 slots
        int t2 = (i - 2) * 512 + tid;
        int hl2 = (t2 >= 768) ? 1 : 0;
        int rem = t2 - 768 * hl2;
        int row = rem >> 3, ss = rem & 7;
        int g = row >> 5, jr = row & 31;
        const unsigned short* s = hl2 ? Wl_s : Wh_s;
        rg[i] = *(const us8*)&s[(g * H_ + jt * 32 + jr) * ldW + kb + ss * 8];
      }
    };
    auto write_phase = [&](int nb) {
#pragma unroll
      for (int i = 0; i < 2; ++i) {
        int t2 = i * 512 + tid;
        int hl2 = t2 >> 9, rem = t2 & 511;
        int rr = rem >> 3, ss = rem & 7;
        *(us8*)&CA[((nb * 2 + hl2) * 64 + rr) * 72 + ss * 8] = rg[i];
      }
#pragma unroll
      for (int i = 2; i < 5; ++i) {
        int t2 = (i - 2) * 512 + tid;
        int hl2 = (t2 >= 768) ? 1 : 0;
        int rem = t2 - 768 * hl2;
        int row = rem >> 3, ss = rem & 7;
        *(us8*)&CW[((nb * 2 + hl2) * 96 + row) * 72 + ss * 8] = rg[i];
      }
    };
    auto compute_phase = [&](int cb, f32x4& accN) {
      __builtin_amdgcn_s_setprio(1);
#pragma unroll
      for (int kk = 0; kk < 64; kk += 32) {
        bf16x8 ah  = *(const bf16x8*)&CA[((cb * 2 + 0) * 64 + wr * 16 + m) * 72 + kk + ko];
        bf16x8 al  = *(const bf16x8*)&CA[((cb * 2 + 1) * 64 + wr * 16 + m) * 72 + kk + ko];
        bf16x8 wrh = *(const bf16x8*)&CW[((cb * 2 + 0) * 96 + wj) * 72 + kk + ko];
        bf16x8 wrl = *(const bf16x8*)&CW[((cb * 2 + 1) * 96 + wj) * 72 + kk + ko];
        bf16x8 wzh = *(const bf16x8*)&CW[((cb * 2 + 0) * 96 + wj + 32) * 72 + kk + ko];
        bf16x8 wzl = *(const bf16x8*)&CW[((cb * 2 + 1) * 96 + wj + 32) * 72 + kk + ko];
        bf16x8 wnh = *(const bf16x8*)&CW[((cb * 2 + 0) * 96 + wj + 64) * 72 + kk + ko];
        bf16x8 wnl = *(const bf16x8*)&CW[((cb * 2 + 1) * 96 + wj + 64) * 72 + kk + ko];
        MFMA(ah, wrh, accR); MFMA(ah, wrl, accR); MFMA(al, wrh, accR);
        MFMA(ah, wzh, accZ); MFMA(ah, wzl, accZ); MFMA(al, wzh, accZ);
        MFMA(ah, wnh, accN); MFMA(ah, wnl, accN); MFMA(al, wnh, accN);
      }
      __builtin_amdgcn_s_setprio(0);
    };

    load_phase(0);
    write_phase(0);
    load_phase(1);
    const int NP = (t > 0) ? 20 : 16;
    for (int p = 0; p < NP; ++p) {
      __syncthreads();
      write_phase((p + 1) & 1);
      int pl = (p + 2 < NP) ? (p + 2) : (NP - 1);
      load_phase(pl);
      if (p < 16) compute_phase(p & 1, accGhn);
      else        compute_phase(p & 1, accGin);
    }

    {  // cell epilogue: gates + h_new
      const int j = jt * 32 + wc * 16 + m;
      const float bir = b_ih[j],          bhr = b_hh[j];
      const float biz = b_ih[H_ + j],     bhz = b_hh[H_ + j];
      const float bin = b_ih[2 * H_ + j], bhn = b_hh[2 * H_ + j];
#pragma unroll
      for (int r2 = 0; r2 < 4; ++r2) {
        int b = bt * 64 + wr * 16 + r0 + r2;
        float gr = accR[r2] + bir + bhr;
        float gz = accZ[r2] + biz + bhz;
        float rr = 1.f / (1.f + __expf(-gr));
        float zz = 1.f / (1.f + __expf(-gz));
        float gn = accGin[r2] + bin + rr * (accGhn[r2] + bhn);
        float nn = tanhf(gn);
        float hold = bf2f(h_h[b * H_ + j]) + bf2f(h_l[b * H_ + j]);
        float hn = (1.f - zz) * nn + zz * hold;
        unsigned short hi = f2bf(hn);
        ho_h[b * H_ + j] = hi;
        ho_l[b * H_ + j] = f2bf(hn - bf2f(hi));
      }
    }

    gbar(bar + 2 * t);   // h(t) visible grid-wide

    // ======================= HEAD =======================
    const unsigned short* hs_h = ho_h;
    const unsigned short* hs_l = ho_l;
    f32x4 acc = {};

    auto h_load = [&](int p) {
      int kb = p << 7;
      {  // A: 2hl x 16 rows x 16 ss = 512 slots (all threads)
        int hl2 = tid >> 8, rem = tid & 255;
        int rr = rem >> 4, ss = rem & 15;
        const unsigned short* s = hl2 ? hs_l : hs_h;
        hg[0] = *(const us8*)&s[(bt2 * 16 + rr) * H_ + kb + ss * 8];
      }
      {  // W hl0: 32 rows x 16 ss = 512 slots
        int ir = tid >> 4, ss = tid & 15;
        hg[1] = *(const us8*)&whd_h[(it * 32 + ir) * H_ + kb + ss * 8];
      }
      {  // W hl1
        int ir = tid >> 4, ss = tid & 15;
        hg[2] = *(const us8*)&whd_l[(it * 32 + ir) * H_ + kb + ss * 8];
      }
    };
    auto h_write = [&](int nb) {
      { int hl2 = tid >> 8, rem = tid & 255;
        int rr = rem >> 4, ss = rem & 15;
        *(us8*)&HA[((nb * 2 + hl2) * 16 + rr) * 136 + ss * 8] = hg[0]; }
      { int ir = tid >> 4, ss = tid & 15;
        *(us8*)&HW[((nb * 2 + 0) * 32 + ir) * 136 + ss * 8] = hg[1]; }
      { int ir = tid >> 4, ss = tid & 15;
        *(us8*)&HW[((nb * 2 + 1) * 32 + ir) * 136 + ss * 8] = hg[2]; }
    };
    auto h_comp = [&](int cb) {
      __builtin_amdgcn_s_setprio(1);
#pragma unroll
      for (int kk = 0; kk < 128; kk += 32) {
        bf16x8 ah = *(const bf16x8*)&HA[((cb * 2 + 0) * 16 + m) * 136 + kk + ko];
        bf16x8 al = *(const bf16x8*)&HA[((cb * 2 + 1) * 16 + m) * 136 + kk + ko];
        bf16x8 wh = *(const bf16x8*)&HW[((cb * 2 + 0) * 32 + wv * 16 + m) * 136 + kk + ko];
        bf16x8 wl = *(const bf16x8*)&HW[((cb * 2 + 1) * 32 + wv * 16 + m) * 136 + kk + ko];
        MFMA(ah, wh, acc); MFMA(ah, wl, acc); MFMA(al, wh, acc);
      }
      __builtin_amdgcn_s_setprio(0);
    };

    h_load(0);
    h_write(0);
    h_load(1);
    for (int p = 0; p < 8; ++p) {
      __syncthreads();
      h_write((p + 1) & 1);
      int pl = (p + 2 < 8) ? (p + 2) : 7;
      h_load(pl);
      if (wv < 2) h_comp(p & 1);   // wave-uniform branch; barriers outside
    }

    if (wv < 2) {  // head epilogue (waves 0-1 only)
      const int i = it * 32 + wv * 16 + m;
      const float bh = b_head[i];
      float* outt = out + (size_t)t * B_ * I_;
#pragma unroll
      for (int r2 = 0; r2 < 4; ++r2) {
        int b = bt2 * 16 + r0 + r2;
        float y = acc[r2] + bh;
        outt[b * I_ + i] = y;
        unsigned short hi = f2bf(y);
        xh[b * I_ + i] = hi;
        xl[b * I_ + i] = f2bf(y - bf2f(hi));
      }
    }

    gbar(bar + 2 * t + 1);   // x(t) visible grid-wide
  }
}

// ---------------------------------------------------------------------------
extern "C" void kernel_launch(void* const* d_in, const int* in_sizes, int n_in,
                              void* d_out, int out_size, void* d_ws, size_t ws_size,
                              hipStream_t stream) {
  (void)in_sizes; (void)n_in; (void)out_size; (void)ws_size;
  const float* ctx    = (const float*)d_in[0];
  // d_in[1] = length (scalar, fixed 256)
  const float* W_ih   = (const float*)d_in[2];
  const float* W_hh   = (const float*)d_in[3];
  const float* b_ih   = (const float*)d_in[4];
  const float* b_hh   = (const float*)d_in[5];
  const float* W_head = (const float*)d_in[6];
  const float* b_head = (const float*)d_in[7];
  float* out = (float*)d_out;

  char* p = (char*)d_ws;
  unsigned short* whh_h = (unsigned short*)p; p += 6291456;
  unsigned short* whh_l = (unsigned short*)p; p += 6291456;
  unsigned short* wih_h = (unsigned short*)p; p += 1572864;
  unsigned short* wih_l = (unsigned short*)p; p += 1572864;
  unsigned short* whd_h = (unsigned short*)p; p += 524288;
  unsigned short* whd_l = (unsigned short*)p; p += 524288;
  unsigned short* hh0 = (unsigned short*)p; p += 1048576;
  unsigned short* hl0 = (unsigned short*)p; p += 1048576;
  unsigned short* hh1 = (unsigned short*)p; p += 1048576;
  unsigned short* hl1 = (unsigned short*)p; p += 1048576;
  unsigned short* xh = (unsigned short*)p; p += 262144;
  unsigned short* xl = (unsigned short*)p; p += 262144;
  unsigned* bar = (unsigned*)p; p += 2048;  // 512 barrier counters
  // total ws used: 21,497,856 bytes

  gru_prep<<<2048, 256, 0, stream>>>(W_hh, W_ih, W_head, ctx,
                                     whh_h, whh_l, wih_h, wih_l, whd_h, whd_l,
                                     hh0, hl0, bar);

  gru_all<<<NBLK, 512, 0, stream>>>(whh_h, whh_l, wih_h, wih_l, whd_h, whd_l,
                                    b_ih, b_hh, b_head,
                                    hh0, hl0, hh1, hl1, xh, xl, out, bar);
}

// Round 11
// 11703.925 us; speedup vs baseline: 2.9099x; 2.9099x over previous
//
#include <hip/hip_runtime.h>

// GRU rollout decoder, MI355X. bf16x3 (hi/lo split) MFMA GEMMs, fp32 accumulate.
// R9/R10: persistent kernel WITHOUT cache-wide invalidation. R7/R8 measured 34ms:
// acquire fences (buffer_inv) nuked L2 -> 23MB/step W refetch from HBM at 3.9%
// MfmaUtil. Fix: no acquire fence ever; cross-step data (h,x) is READ via
// agent-scope relaxed atomic loads (coherent, bypass stale L2 per-access);
// writes stay normal cached + release fence (buffer_wbl2, writeback-ONLY) in
// gbar before flag add. W stays L2-resident across all 256 steps.
// Also: hold kept in registers across steps (block's own output tile).

typedef __attribute__((ext_vector_type(8))) short bf16x8;
typedef __attribute__((ext_vector_type(4))) float f32x4;
typedef __attribute__((ext_vector_type(8))) unsigned short us8;
typedef unsigned long long u64_t;
union UQ { u64_t q[2]; us8 v; };

#define I_ 256
#define H_ 1024
#define B_ 512
#define L_ 256
#define NBLK 256

#define MFMA(A, Bm, C) C = __builtin_amdgcn_mfma_f32_16x16x32_bf16(A, Bm, C, 0, 0, 0)

__device__ __forceinline__ unsigned short f2bf(float f) {
  unsigned u = __float_as_uint(f);
  u += 0x7FFFu + ((u >> 16) & 1u);   // round-to-nearest-even
  return (unsigned short)(u >> 16);
}
__device__ __forceinline__ float bf2f(unsigned short s) {
  return __uint_as_float(((unsigned)s) << 16);
}
__device__ __forceinline__ u64_t cohload(const unsigned short* p) {
  return __hip_atomic_load((const u64_t*)p, __ATOMIC_RELAXED, __HIP_MEMORY_SCOPE_AGENT);
}

// ---------------------------------------------------------------------------
// prep: split W_hh, W_ih, W_head, context into bf16 hi/lo pairs; zero barriers
// ---------------------------------------------------------------------------
__global__ void gru_prep(const float* __restrict__ whh, const float* __restrict__ wih,
                         const float* __restrict__ whd, const float* __restrict__ ctx,
                         unsigned short* __restrict__ whh_h, unsigned short* __restrict__ whh_l,
                         unsigned short* __restrict__ wih_h, unsigned short* __restrict__ wih_l,
                         unsigned short* __restrict__ whd_h, unsigned short* __restrict__ whd_l,
                         unsigned short* __restrict__ hh, unsigned short* __restrict__ hl,
                         unsigned* __restrict__ bar) {
  const int gid = blockIdx.x * blockDim.x + threadIdx.x;
  if (gid < 2 * L_) bar[gid] = 0;
  const int NWHH = 3 * H_ * H_;
  const int NWIH = 3 * H_ * I_;
  const int NWHD = I_ * H_;
  const int NCTX = B_ * H_;
  const int tot = NWHH + NWIH + NWHD + NCTX;
  for (int idx = gid; idx < tot; idx += gridDim.x * blockDim.x) {
    const float* src; unsigned short* dh; unsigned short* dl; int off;
    if (idx < NWHH) { src = whh; dh = whh_h; dl = whh_l; off = idx; }
    else if (idx < NWHH + NWIH) { src = wih; dh = wih_h; dl = wih_l; off = idx - NWHH; }
    else if (idx < NWHH + NWIH + NWHD) { src = whd; dh = whd_h; dl = whd_l; off = idx - NWHH - NWIH; }
    else { src = ctx; dh = hh; dl = hl; off = idx - NWHH - NWIH - NWHD; }
    float v = src[off];
    unsigned short h = f2bf(v);
    dh[off] = h;
    dl[off] = f2bf(v - bf2f(h));
  }
}

// ---------------------------------------------------------------------------
// grid barrier, no-invalidate flavor: __syncthreads drains each wave's stores
// into L2; thread0 release-fence (buffer_wbl2: writeback only, L2 stays valid)
// pushes them to the coherence point; relaxed add + spin; no acquire fence
// (consumers use coherent atomic loads for cross-block data instead).
// ---------------------------------------------------------------------------
__device__ __forceinline__ void gbar(unsigned* cnt) {
  __syncthreads();
  if (threadIdx.x == 0) {
    __builtin_amdgcn_fence(__ATOMIC_RELEASE, "agent");   // wbl2, no inv
    __hip_atomic_fetch_add(cnt, 1u, __ATOMIC_RELAXED, __HIP_MEMORY_SCOPE_AGENT);
    while (__hip_atomic_load(cnt, __ATOMIC_RELAXED, __HIP_MEMORY_SCOPE_AGENT) < (unsigned)NBLK)
      __builtin_amdgcn_s_sleep(8);
  }
  __syncthreads();
  asm volatile("" ::: "memory");
}

// ---------------------------------------------------------------------------
// persistent kernel: 256 blocks x 512 threads, loops t=0..255.
//   CELL (BM=64 x BN=32, 8 waves 4x2, K-step 64) -> gbar -> HEAD (16x32) -> gbar
// h/x loads: coherent atomic u64 pairs. W/bias loads: normal (L2-resident).
// h/x/out stores: normal (pushed by gbar's release fence).
// ---------------------------------------------------------------------------
__global__ __launch_bounds__(512) void gru_all(
    const float* __restrict__ ctx,
    const unsigned short* __restrict__ whh_h, const unsigned short* __restrict__ whh_l,
    const unsigned short* __restrict__ wih_h, const unsigned short* __restrict__ wih_l,
    const unsigned short* __restrict__ whd_h, const unsigned short* __restrict__ whd_l,
    const float* __restrict__ b_ih, const float* __restrict__ b_hh,
    const float* __restrict__ b_head,
    unsigned short* hh0, unsigned short* hl0,
    unsigned short* hh1, unsigned short* hl1,
    unsigned short* xh, unsigned short* xl,
    float* out, unsigned* bar) {
  __shared__ __align__(16) unsigned char smem[92160];
  unsigned short* CA = (unsigned short*)smem;            // cell A [nb][hl][64][72]
  unsigned short* CW = (unsigned short*)(smem + 36864);  // cell W [nb][hl][96][72]
  unsigned short* HA = (unsigned short*)smem;            // head A [nb][hl][16][136]
  unsigned short* HW = (unsigned short*)(smem + 17408);  // head W [nb][hl][32][136]

  const int tid = threadIdx.x;
  const int bid = blockIdx.x;
  const int xcd = bid & 7;
  const int q = bid >> 3;                 // 0..31
  const int jt = xcd * 4 + (q & 3);       // 0..31  h-col tile (32 cols)
  const int bt = q >> 2;                  // 0..7   batch tile (64 rows)
  const int wv = tid >> 6;                // wave 0..7
  const int wr = wv >> 1;                 // 16-row frag (0..3)
  const int wc = wv & 1;                  // 16-col half (0..1)
  const int lane = tid & 63;
  const int m = lane & 15;
  const int ko = (lane >> 4) << 3;        // 0,8,16,24 within 32-k chunk
  const int wj = wc * 16 + m;             // col within 32-col gate block
  const int r0 = (lane >> 4) << 2;
  const int it = bid & 7;                 // head: i tile (32 cols)
  const int bt2 = bid >> 3;               // head: batch tile (16 rows)

  us8 rg[5];   // cell staging
  us8 hg[3];   // head staging

  // persistent hold: this block's own h_new tile from last step (fp32).
  const int jglob = jt * 32 + wc * 16 + m;
  float hold[4];
#pragma unroll
  for (int r2 = 0; r2 < 4; ++r2)
    hold[r2] = ctx[(bt * 64 + wr * 16 + r0 + r2) * H_ + jglob];

#pragma unroll 1
  for (int t = 0; t < L_; ++t) {
    const unsigned short* h_h = (t & 1) ? hh1 : hh0;
    const unsigned short* h_l = (t & 1) ? hl1 : hl0;
    unsigned short* ho_h = (t & 1) ? hh0 : hh1;
    unsigned short* ho_l = (t & 1) ? hl0 : hl1;

    // ======================= CELL =======================
    f32x4 accR = {}, accZ = {}, accGin = {}, accGhn = {};

    auto load_phase = [&](int p) {
      const unsigned short *Ah_s, *Al_s, *Wh_s, *Wl_s;
      int kb, ldA, ldW;
      if (p < 16) { Ah_s = h_h; Al_s = h_l; Wh_s = whh_h; Wl_s = whh_l; kb = p << 6; ldA = H_; ldW = H_; }
      else        { Ah_s = xh;  Al_s = xl;  Wh_s = wih_h; Wl_s = wih_l; kb = (p - 16) << 6; ldA = I_; ldW = I_; }
#pragma unroll
      for (int i = 0; i < 2; ++i) {  // A (h/x): coherent atomic loads
        int t2 = i * 512 + tid;
        int hl2 = t2 >> 9, rem = t2 & 511;
        int rr = rem >> 3, ss = rem & 7;
        const unsigned short* s = hl2 ? Al_s : Ah_s;
        const unsigned short* sp = &s[(bt * 64 + rr) * ldA + kb + ss * 8];
        UQ u;
        u.q[0] = cohload(sp);
        u.q[1] = cohload(sp + 4);
        rg[i] = u.v;
      }
#pragma unroll
      for (int i = 2; i < 5; ++i) {  // W: normal cached loads (L2-resident)
        int t2 = (i - 2) * 512 + tid;
        int hl2 = (t2 >= 768) ? 1 : 0;
        int rem = t2 - 768 * hl2;
        int row = rem >> 3, ss = rem & 7;
        int g = row >> 5, jr = row & 31;
        const unsigned short* s = hl2 ? Wl_s : Wh_s;
        rg[i] = *(const us8*)&s[(g * H_ + jt * 32 + jr) * ldW + kb + ss * 8];
      }
    };
    auto write_phase = [&](int nb) {
#pragma unroll
      for (int i = 0; i < 2; ++i) {
        int t2 = i * 512 + tid;
        int hl2 = t2 >> 9, rem = t2 & 511;
        int rr = rem >> 3, ss = rem & 7;
        *(us8*)&CA[((nb * 2 + hl2) * 64 + rr) * 72 + ss * 8] = rg[i];
      }
#pragma unroll
      for (int i = 2; i < 5; ++i) {
        int t2 = (i - 2) * 512 + tid;
        int hl2 = (t2 >= 768) ? 1 : 0;
        int rem = t2 - 768 * hl2;
        int row = rem >> 3, ss = rem & 7;
        *(us8*)&CW[((nb * 2 + hl2) * 96 + row) * 72 + ss * 8] = rg[i];
      }
    };
    auto compute_phase = [&](int cb, f32x4& accN) {
      __builtin_amdgcn_s_setprio(1);
#pragma unroll
      for (int kk = 0; kk < 64; kk += 32) {
        bf16x8 ah  = *(const bf16x8*)&CA[((cb * 2 + 0) * 64 + wr * 16 + m) * 72 + kk + ko];
        bf16x8 al  = *(const bf16x8*)&CA[((cb * 2 + 1) * 64 + wr * 16 + m) * 72 + kk + ko];
        bf16x8 wrh = *(const bf16x8*)&CW[((cb * 2 + 0) * 96 + wj) * 72 + kk + ko];
        bf16x8 wrl = *(const bf16x8*)&CW[((cb * 2 + 1) * 96 + wj) * 72 + kk + ko];
        bf16x8 wzh = *(const bf16x8*)&CW[((cb * 2 + 0) * 96 + wj + 32) * 72 + kk + ko];
        bf16x8 wzl = *(const bf16x8*)&CW[((cb * 2 + 1) * 96 + wj + 32) * 72 + kk + ko];
        bf16x8 wnh = *(const bf16x8*)&CW[((cb * 2 + 0) * 96 + wj + 64) * 72 + kk + ko];
        bf16x8 wnl = *(const bf16x8*)&CW[((cb * 2 + 1) * 96 + wj + 64) * 72 + kk + ko];
        MFMA(ah, wrh, accR); MFMA(ah, wrl, accR); MFMA(al, wrh, accR);
        MFMA(ah, wzh, accZ); MFMA(ah, wzl, accZ); MFMA(al, wzh, accZ);
        MFMA(ah, wnh, accN); MFMA(ah, wnl, accN); MFMA(al, wnh, accN);
      }
      __builtin_amdgcn_s_setprio(0);
    };

    load_phase(0);
    write_phase(0);
    load_phase(1);
    const int NP = (t > 0) ? 20 : 16;
    for (int p = 0; p < NP; ++p) {
      __syncthreads();
      write_phase((p + 1) & 1);
      int pl = (p + 2 < NP) ? (p + 2) : (NP - 1);
      load_phase(pl);
      if (p < 16) compute_phase(p & 1, accGhn);
      else        compute_phase(p & 1, accGin);
    }

    {  // cell epilogue: gates + h_new (hold from registers)
      const float bir = b_ih[jglob],          bhr = b_hh[jglob];
      const float biz = b_ih[H_ + jglob],     bhz = b_hh[H_ + jglob];
      const float bin = b_ih[2 * H_ + jglob], bhn = b_hh[2 * H_ + jglob];
#pragma unroll
      for (int r2 = 0; r2 < 4; ++r2) {
        int b = bt * 64 + wr * 16 + r0 + r2;
        float gr = accR[r2] + bir + bhr;
        float gz = accZ[r2] + biz + bhz;
        float rr = 1.f / (1.f + __expf(-gr));
        float zz = 1.f / (1.f + __expf(-gz));
        float gn = accGin[r2] + bin + rr * (accGhn[r2] + bhn);
        float nn = tanhf(gn);
        float hn = (1.f - zz) * nn + zz * hold[r2];
        hold[r2] = hn;
        unsigned short hi = f2bf(hn);
        ho_h[b * H_ + jglob] = hi;
        ho_l[b * H_ + jglob] = f2bf(hn - bf2f(hi));
      }
    }

    gbar(bar + 2 * t);   // h(t) pushed to coherence point, grid-wide arrival

    // ======================= HEAD =======================
    const unsigned short* hs_h = ho_h;
    const unsigned short* hs_l = ho_l;
    f32x4 acc = {};

    auto h_load = [&](int p) {
      int kb = p << 7;
      {  // A (h): coherent atomic loads
        int hl2 = tid >> 8, rem = tid & 255;
        int rr = rem >> 4, ss = rem & 15;
        const unsigned short* s = hl2 ? hs_l : hs_h;
        const unsigned short* sp = &s[(bt2 * 16 + rr) * H_ + kb + ss * 8];
        UQ u;
        u.q[0] = cohload(sp);
        u.q[1] = cohload(sp + 4);
        hg[0] = u.v;
      }
      {  // W hl0: normal cached
        int ir = tid >> 4, ss = tid & 15;
        hg[1] = *(const us8*)&whd_h[(it * 32 + ir) * H_ + kb + ss * 8];
      }
      {  // W hl1
        int ir = tid >> 4, ss = tid & 15;
        hg[2] = *(const us8*)&whd_l[(it * 32 + ir) * H_ + kb + ss * 8];
      }
    };
    auto h_write = [&](int nb) {
      { int hl2 = tid >> 8, rem = tid & 255;
        int rr = rem >> 4, ss = rem & 15;
        *(us8*)&HA[((nb * 2 + hl2) * 16 + rr) * 136 + ss * 8] = hg[0]; }
      { int ir = tid >> 4, ss = tid & 15;
        *(us8*)&HW[((nb * 2 + 0) * 32 + ir) * 136 + ss * 8] = hg[1]; }
      { int ir = tid >> 4, ss = tid & 15;
        *(us8*)&HW[((nb * 2 + 1) * 32 + ir) * 136 + ss * 8] = hg[2]; }
    };
    auto h_comp = [&](int cb) {
      __builtin_amdgcn_s_setprio(1);
#pragma unroll
      for (int kk = 0; kk < 128; kk += 32) {
        bf16x8 ah = *(const bf16x8*)&HA[((cb * 2 + 0) * 16 + m) * 136 + kk + ko];
        bf16x8 al = *(const bf16x8*)&HA[((cb * 2 + 1) * 16 + m) * 136 + kk + ko];
        bf16x8 wh = *(const bf16x8*)&HW[((cb * 2 + 0) * 32 + wv * 16 + m) * 136 + kk + ko];
        bf16x8 wl = *(const bf16x8*)&HW[((cb * 2 + 1) * 32 + wv * 16 + m) * 136 + kk + ko];
        MFMA(ah, wh, acc); MFMA(ah, wl, acc); MFMA(al, wh, acc);
      }
      __builtin_amdgcn_s_setprio(0);
    };

    h_load(0);
    h_write(0);
    h_load(1);
    for (int p = 0; p < 8; ++p) {
      __syncthreads();
      h_write((p + 1) & 1);
      int pl = (p + 2 < 8) ? (p + 2) : 7;
      h_load(pl);
      if (wv < 2) h_comp(p & 1);   // wave-uniform branch; barriers outside
    }

    if (wv < 2) {  // head epilogue (waves 0-1 only)
      const int i = it * 32 + wv * 16 + m;
      const float bh = b_head[i];
      float* outt = out + (size_t)t * B_ * I_;
#pragma unroll
      for (int r2 = 0; r2 < 4; ++r2) {
        int b = bt2 * 16 + r0 + r2;
        float y = acc[r2] + bh;
        outt[b * I_ + i] = y;
        unsigned short hi = f2bf(y);
        xh[b * I_ + i] = hi;
        xl[b * I_ + i] = f2bf(y - bf2f(hi));
      }
    }

    gbar(bar + 2 * t + 1);   // x(t) pushed to coherence point
  }
}

// ---------------------------------------------------------------------------
extern "C" void kernel_launch(void* const* d_in, const int* in_sizes, int n_in,
                              void* d_out, int out_size, void* d_ws, size_t ws_size,
                              hipStream_t stream) {
  (void)in_sizes; (void)n_in; (void)out_size; (void)ws_size;
  const float* ctx    = (const float*)d_in[0];
  // d_in[1] = length (scalar, fixed 256)
  const float* W_ih   = (const float*)d_in[2];
  const float* W_hh   = (const float*)d_in[3];
  const float* b_ih   = (const float*)d_in[4];
  const float* b_hh   = (const float*)d_in[5];
  const float* W_head = (const float*)d_in[6];
  const float* b_head = (const float*)d_in[7];
  float* out = (float*)d_out;

  char* p = (char*)d_ws;
  unsigned short* whh_h = (unsigned short*)p; p += 6291456;
  unsigned short* whh_l = (unsigned short*)p; p += 6291456;
  unsigned short* wih_h = (unsigned short*)p; p += 1572864;
  unsigned short* wih_l = (unsigned short*)p; p += 1572864;
  unsigned short* whd_h = (unsigned short*)p; p += 524288;
  unsigned short* whd_l = (unsigned short*)p; p += 524288;
  unsigned short* hh0 = (unsigned short*)p; p += 1048576;
  unsigned short* hl0 = (unsigned short*)p; p += 1048576;
  unsigned short* hh1 = (unsigned short*)p; p += 1048576;
  unsigned short* hl1 = (unsigned short*)p; p += 1048576;
  unsigned short* xh = (unsigned short*)p; p += 262144;
  unsigned short* xl = (unsigned short*)p; p += 262144;
  unsigned* bar = (unsigned*)p; p += 2048;  // 512 barrier counters
  // total ws used: 21,497,856 bytes

  gru_prep<<<2048, 256, 0, stream>>>(W_hh, W_ih, W_head, ctx,
                                     whh_h, whh_l, wih_h, wih_l, whd_h, whd_l,
                                     hh0, hl0, bar);

  gru_all<<<NBLK, 512, 0, stream>>>(ctx,
                                    whh_h, whh_l, wih_h, wih_l, whd_h, whd_l,
                                    b_ih, b_hh, b_head,
                                    hh0, hl0, hh1, hl1, xh, xl, out, bar);
}